// Round 13
// baseline (190.312 us; speedup 1.0000x reference)
//
#include <hip/hip_runtime.h>
#include <hip/hip_bf16.h>

#define NN   4096
#define FIN  512
#define FOUT 64
#define NH   8
#define ALPHA 0.2f
#define ROWS 128
#define LOG2E 1.4426950408889634f

typedef __attribute__((ext_vector_type(8))) short bf16x8;
typedef __attribute__((ext_vector_type(4))) float f32x4;

__device__ __forceinline__ unsigned short f2bf(float x) {
    unsigned u = __float_as_uint(x);
    return (unsigned short)((u + 0x7fffu + ((u >> 16) & 1u)) >> 16);  // RNE
}

__device__ __forceinline__ unsigned pk2(float a, float b) {
    union { __hip_bfloat162 h2; unsigned u; } cv;
    cv.h2 = __float22bfloat162_rn(float2{a, b});   // low 16 = a (RNE)
    return cv.u;
}

// ---------------------------------------------------------------------------
// KB: adj -> 64-bit masks. (Proven R8 kernel, unchanged.)
// ---------------------------------------------------------------------------
__global__ __launch_bounds__(256) void kb(const int* __restrict__ adj,
                                          unsigned long long* __restrict__ bits) {
    const int wv   = blockIdx.x * 4 + (threadIdx.x >> 6);
    const int lane = threadIdx.x & 63;
    const int base = wv * 32;
    #pragma unroll
    for (int r = 0; r < 4; ++r) {
        int v0 = adj[(size_t)(base + r*8 + 0) * 64 + lane];
        int v1 = adj[(size_t)(base + r*8 + 1) * 64 + lane];
        int v2 = adj[(size_t)(base + r*8 + 2) * 64 + lane];
        int v3 = adj[(size_t)(base + r*8 + 3) * 64 + lane];
        int v4 = adj[(size_t)(base + r*8 + 4) * 64 + lane];
        int v5 = adj[(size_t)(base + r*8 + 5) * 64 + lane];
        int v6 = adj[(size_t)(base + r*8 + 6) * 64 + lane];
        int v7 = adj[(size_t)(base + r*8 + 7) * 64 + lane];
        unsigned long long m0 = __ballot(v0 > 0);
        unsigned long long m1 = __ballot(v1 > 0);
        unsigned long long m2 = __ballot(v2 > 0);
        unsigned long long m3 = __ballot(v3 > 0);
        unsigned long long m4 = __ballot(v4 > 0);
        unsigned long long m5 = __ballot(v5 > 0);
        unsigned long long m6 = __ballot(v6 > 0);
        unsigned long long m7 = __ballot(v7 > 0);
        if (lane == 0) {
            ulonglong2* dst = (ulonglong2*)&bits[base + r*8];
            dst[0] = {m0, m1};
            dst[1] = {m2, m3};
            dst[2] = {m4, m5};
            dst[3] = {m6, m7};
        }
    }
}

// ---------------------------------------------------------------------------
// KG: Wh GEMM + WhTs epilogue. f1/f2 now stored as 4 exp2-factor arrays:
//   E1=2^(f1*log2e), F1=2^(α f1*log2e), E2=2^(f2*log2e), F2=2^(α f2*log2e)
// so k3's p = max(E1[i]E2[j], F1[i]F2[j])  (exp2∘leakyrelu factorized;
// exp2 monotone + lrelu = max of two linear forms).
// ---------------------------------------------------------------------------
__global__ __launch_bounds__(256) void kg(const float* __restrict__ x,
                                          const float* __restrict__ W,
                                          const float* __restrict__ aw,
                                          unsigned short* __restrict__ WhTs,
                                          float* __restrict__ E1,
                                          float* __restrict__ F1,
                                          float* __restrict__ E2,
                                          float* __restrict__ F2) {
    __shared__ float As[16][68];
    __shared__ float Bs[16][68];
    __shared__ unsigned short Tb[64][80];
    __shared__ float r1[64][16];
    __shared__ float r2[64][16];
    const int t = threadIdx.x;
    const int bx   = blockIdx.x;             // 0..511
    const int h    = bx >> 6;
    const int nti  = bx & 63;
    const int row0 = nti * 64;
    const int tr = t >> 4, tc = t & 15;
    const int ar = t >> 2, ak = t & 3;
    const int bk = t >> 4, bo = t & 15;
    const float* WH = W + (size_t)h * FIN * FOUT;
    float acc[4][4] = {};

    for (int k0i = 0; k0i < FIN; k0i += 16) {
        __syncthreads();
        float4 av = *(const float4*)&x[(size_t)(row0 + ar) * FIN + k0i + ak * 4];
        As[ak*4+0][ar] = av.x; As[ak*4+1][ar] = av.y;
        As[ak*4+2][ar] = av.z; As[ak*4+3][ar] = av.w;
        *(float4*)&Bs[bk][bo*4] =
            *(const float4*)&WH[(size_t)(k0i + bk) * FOUT + bo*4];
        __syncthreads();
        #pragma unroll
        for (int kk = 0; kk < 16; ++kk) {
            float4 a4 = *(const float4*)&As[kk][tr*4];
            float4 b4 = *(const float4*)&Bs[kk][tc*4];
            float a[4] = {a4.x, a4.y, a4.z, a4.w};
            float b[4] = {b4.x, b4.y, b4.z, b4.w};
            #pragma unroll
            for (int i = 0; i < 4; ++i)
                #pragma unroll
                for (int j = 0; j < 4; ++j)
                    acc[i][j] = fmaf(a[i], b[j], acc[i][j]);
        }
    }

    float a1v[4], a2v[4];
    #pragma unroll
    for (int j = 0; j < 4; ++j) {
        a1v[j] = aw[h * 2 * FOUT + tc*4 + j];
        a2v[j] = aw[h * 2 * FOUT + FOUT + tc*4 + j];
    }
    #pragma unroll
    for (int i = 0; i < 4; ++i) {
        float s1 = 0.f, s2 = 0.f;
        #pragma unroll
        for (int j = 0; j < 4; ++j) {
            s1 = fmaf(acc[i][j], a1v[j], s1);
            s2 = fmaf(acc[i][j], a2v[j], s2);
            Tb[tc*4 + j][tr*4 + i] = f2bf(acc[i][j]);
        }
        r1[tr*4 + i][tc] = s1;
        r2[tr*4 + i][tc] = s2;
    }
    __syncthreads();
    if (t < 64) {
        float s1 = 0.f, s2 = 0.f;
        #pragma unroll
        for (int k = 0; k < 16; ++k) { s1 += r1[t][k]; s2 += r2[t][k]; }
        float a = s1 * LOG2E, b = s2 * LOG2E;
        E1[h * NN + row0 + t] = __builtin_amdgcn_exp2f(a);
        F1[h * NN + row0 + t] = __builtin_amdgcn_exp2f(ALPHA * a);
        E2[h * NN + row0 + t] = __builtin_amdgcn_exp2f(b);
        F2[h * NN + row0 + t] = __builtin_amdgcn_exp2f(ALPHA * b);
    }
    unsigned char* tileB = (unsigned char*)(WhTs + ((size_t)(h * 64) + nti) * 4096);
    #pragma unroll
    for (int i = 0; i < 2; ++i) {
        int c = t + i * 256;
        int o = c >> 3, nch = c & 7;
        *(uint4*)(tileB + o * 128 + ((nch * 16) ^ ((o & 7) << 4))) =
            *(const uint4*)&Tb[o][nch * 8];
    }
}

// ---------------------------------------------------------------------------
// K3: fused masked softmax + PV (bf16 MFMA), j-split. 2-barrier template,
// 512 thr / 8 waves / ROWS=128. P computed DIRECTLY into each lane's MFMA
// A-fragment (row = wid*16+(lane&15), cols = ks*32+(lane>>4)*8+{0..7}) —
// no psB LDS at all. p = max(E1r*E2[j], F1r*F2[j]) masked by adj bit.
// Denominator via MFMA with constant ones-B fragment.
// ---------------------------------------------------------------------------
__global__ __launch_bounds__(512, 8) void k3_attn(
        const unsigned long long* __restrict__ bits,
        const unsigned short* __restrict__ WhTs,
        const float* __restrict__ E1, const float* __restrict__ F1,
        const float* __restrict__ E2, const float* __restrict__ F2,
        float* __restrict__ pnum, float* __restrict__ pden) {
    __shared__ unsigned char wsB[8192];
    const int t    = threadIdx.x;
    const int lane = t & 63, wid = t >> 6;      // 8 waves
    const int h    = blockIdx.y;
    const int row0 = blockIdx.x * ROWS;
    const int js   = blockIdx.z, JS = gridDim.z;
    const int ntile = (NN / 64) / JS;
    const int nt0   = js * ntile;
    const int myrow = wid * 16 + (lane & 15);   // block-local row 0..127
    const int kq    = lane >> 4;                // col-quarter 0..3
    const float E1r = E1[h * NN + row0 + myrow];
    const float F1r = F1[h * NN + row0 + myrow];
    const float* E2h = E2 + h * NN;
    const float* F2h = F2 + h * NN;
    const unsigned long long* bitsRow = bits + (size_t)(row0 + myrow) * 64;
    const unsigned short* WTS = WhTs + (size_t)h * 64 * 4096;
    f32x4 acc[4] = {};
    f32x4 accd = {};
    const bf16x8 ones = {0x3F80, 0x3F80, 0x3F80, 0x3F80,
                         0x3F80, 0x3F80, 0x3F80, 0x3F80};   // bf16 1.0 x8

    uint4 wreg;
    auto loadW = [&](int nti, uint4& w0) {
        w0 = ((const uint4*)(WTS + (size_t)nti * 4096))[t];   // 512 x 16B = 8 KB
    };
    loadW(nt0, wreg);

    for (int it = 0; it < ntile; ++it) {
        const int nti = nt0 + it;
        __syncthreads();                       // prev MFMA done reading wsB
        *(uint4*)&wsB[t * 16] = wreg;
        // ---- P directly into A-fragments ----
        const unsigned long long m64 = bitsRow[nti];
        union { uint4 u; bf16x8 v; } af[2];
        #pragma unroll
        for (int ks = 0; ks < 2; ++ks) {
            const int c0 = nti * 64 + ks * 32 + kq * 8;
            float4 ea = *(const float4*)&E2h[c0];
            float4 eb = *(const float4*)&E2h[c0 + 4];
            float4 fa = *(const float4*)&F2h[c0];
            float4 fb = *(const float4*)&F2h[c0 + 4];
            const unsigned mb = (unsigned)(m64 >> (ks * 32 + kq * 8)) & 0xFFu;
            float p0 = (mb &   1u) ? fmaxf(E1r * ea.x, F1r * fa.x) : 0.f;
            float p1 = (mb &   2u) ? fmaxf(E1r * ea.y, F1r * fa.y) : 0.f;
            float p2 = (mb &   4u) ? fmaxf(E1r * ea.z, F1r * fa.z) : 0.f;
            float p3 = (mb &   8u) ? fmaxf(E1r * ea.w, F1r * fa.w) : 0.f;
            float p4 = (mb &  16u) ? fmaxf(E1r * eb.x, F1r * fb.x) : 0.f;
            float p5 = (mb &  32u) ? fmaxf(E1r * eb.y, F1r * fb.y) : 0.f;
            float p6 = (mb &  64u) ? fmaxf(E1r * eb.z, F1r * fb.z) : 0.f;
            float p7 = (mb & 128u) ? fmaxf(E1r * eb.w, F1r * fb.w) : 0.f;
            af[ks].u = uint4{pk2(p0, p1), pk2(p2, p3), pk2(p4, p5), pk2(p6, p7)};
        }
        if (it + 1 < ntile) loadW(nti + 1, wreg);
        __syncthreads();                       // wsB visible
        {
            const int kbyte = kq * 16;
            #pragma unroll
            for (int ks = 0; ks < 2; ++ks) {
                accd = __builtin_amdgcn_mfma_f32_16x16x32_bf16(af[ks].v, ones, accd, 0, 0, 0);
                #pragma unroll
                for (int cf = 0; cf < 4; ++cf) {
                    int brw = cf * 16 + (lane & 15);
                    bf16x8 bfr = *(const bf16x8*)&wsB[brw * 128 + ((ks*64 + kbyte) ^ ((brw & 7) << 4))];
                    acc[cf] = __builtin_amdgcn_mfma_f32_16x16x32_bf16(af[ks].v, bfr, acc[cf], 0, 0, 0);
                }
            }
        }
    }

    float* pn = pnum + (((size_t)js * NH + h) * NN + row0) * 64;
    #pragma unroll
    for (int cf = 0; cf < 4; ++cf) {
        int o = cf * 16 + (lane & 15);
        #pragma unroll
        for (int rg = 0; rg < 4; ++rg) {
            int rl = wid * 16 + (lane >> 4) * 4 + rg;
            pn[(size_t)rl * 64 + o] = acc[cf][rg];
        }
    }
    if ((lane & 15) == 0) {                    // col-0 lanes hold den[row]
        float* pd = pden + ((size_t)js * NH + h) * NN + row0;
        #pragma unroll
        for (int rg = 0; rg < 4; ++rg)
            pd[wid * 16 + (lane >> 4) * 4 + rg] = accd[rg];
    }
}

// ---------------------------------------------------------------------------
// K4: reduce over JS slices + normalize.
// ---------------------------------------------------------------------------
__global__ __launch_bounds__(256) void k4_red(const float* __restrict__ pnum,
                                              const float* __restrict__ pden,
                                              float* __restrict__ out, int JS) {
    const int idx = blockIdx.x * 256 + threadIdx.x;   // 0..524287
    const int h   = idx >> 16;
    const int rem = idx & 65535;
    const int n   = rem >> 4;
    const int o4  = (rem & 15) * 4;
    float4 s = {0.f, 0.f, 0.f, 0.f};
    float  d = 0.f;
    for (int js = 0; js < JS; ++js) {
        const float* p = pnum + (((size_t)js * NH + h) * NN + n) * 64 + o4;
        float4 v = *(const float4*)p;
        s.x += v.x; s.y += v.y; s.z += v.z; s.w += v.w;
        d += pden[((size_t)js * NH + h) * NN + n];
    }
    float inv = 1.0f / d;
    float4 r = {s.x * inv, s.y * inv, s.z * inv, s.w * inv};
    *(float4*)&out[(size_t)n * (NH * FOUT) + h * FOUT + o4] = r;
}

extern "C" void kernel_launch(void* const* d_in, const int* in_sizes, int n_in,
                              void* d_out, int out_size, void* d_ws, size_t ws_size,
                              hipStream_t stream) {
    const float* x   = (const float*)d_in[0];
    const int*   adj = (const int*)d_in[1];
    const float* W   = (const float*)d_in[2];
    const float* a   = (const float*)d_in[3];
    float* outp = (float*)d_out;

    // workspace layout
    unsigned short* WhTs = (unsigned short*)d_ws;                   // 4 MB (tiled)
    float* E1 = (float*)(WhTs + (size_t)NH * 64 * NN);              // 128 KB each
    float* F1 = E1 + NH * NN;
    float* E2 = F1 + NH * NN;
    float* F2 = E2 + NH * NN;
    unsigned long long* bits = (unsigned long long*)(F2 + NH * NN); // 2 MB
    float* pnum = (float*)(bits + (size_t)NN * 64);
    const size_t baseBytes  = (size_t)((char*)pnum - (char*)d_ws);
    const size_t sliceBytes = (size_t)NH * NN * 65 * 4;             // num+den per slice
    int JS = 1;
    if (ws_size >= baseBytes + 4 * sliceBytes) JS = 4;
    else if (ws_size >= baseBytes + 2 * sliceBytes) JS = 2;
    float* pden = pnum + (size_t)JS * NH * NN * 64;

    kb     <<<dim3(2048),            256, 0, stream>>>(adj, bits);
    kg     <<<dim3(512),             256, 0, stream>>>(x, W, a, WhTs, E1, F1, E2, F2);
    k3_attn<<<dim3(NN/ROWS, NH, JS), 512, 0, stream>>>(bits, WhTs, E1, F1, E2, F2, pnum, pden);
    k4_red <<<dim3(NN*NH*FOUT/4/256), 256, 0, stream>>>(pnum, pden, outp, JS);
}

// Round 14
// 179.548 us; speedup vs baseline: 1.0600x; 1.0600x over previous
//
#include <hip/hip_runtime.h>
#include <hip/hip_bf16.h>

#define NN   4096
#define FIN  512
#define FOUT 64
#define NH   8
#define ALPHA 0.2f
#define ROWS 128
#define LOG2E 1.4426950408889634f

typedef __attribute__((ext_vector_type(8))) short bf16x8;
typedef __attribute__((ext_vector_type(4))) float f32x4;

__device__ __forceinline__ unsigned short f2bf(float x) {
    unsigned u = __float_as_uint(x);
    return (unsigned short)((u + 0x7fffu + ((u >> 16) & 1u)) >> 16);  // RNE
}

__device__ __forceinline__ unsigned pk2(float a, float b) {
    union { __hip_bfloat162 h2; unsigned u; } cv;
    cv.h2 = __float22bfloat162_rn(float2{a, b});   // low 16 = a (RNE)
    return cv.u;
}

__device__ __forceinline__ bf16x8 u4bf8(uint4 u) {   // scalar union: SROA-safe
    union { uint4 a; bf16x8 b; } cv; cv.a = u; return cv.b;
}

// Build one A-fragment (8 bf16 P values) from factored exp2 terms.
// p[j] = adjbit ? max(E1r*E2[j], F1r*F2[j]) : 0   (exp2∘lrelu factorized)
__device__ __forceinline__ bf16x8 mkaf(float E1r, float F1r,
                                       const float* __restrict__ E2p,
                                       const float* __restrict__ F2p,
                                       unsigned mb) {
    float4 ea = *(const float4*)E2p;
    float4 eb = *(const float4*)(E2p + 4);
    float4 fa = *(const float4*)F2p;
    float4 fb = *(const float4*)(F2p + 4);
    float p0 = (mb &   1u) ? fmaxf(E1r * ea.x, F1r * fa.x) : 0.f;
    float p1 = (mb &   2u) ? fmaxf(E1r * ea.y, F1r * fa.y) : 0.f;
    float p2 = (mb &   4u) ? fmaxf(E1r * ea.z, F1r * fa.z) : 0.f;
    float p3 = (mb &   8u) ? fmaxf(E1r * ea.w, F1r * fa.w) : 0.f;
    float p4 = (mb &  16u) ? fmaxf(E1r * eb.x, F1r * fb.x) : 0.f;
    float p5 = (mb &  32u) ? fmaxf(E1r * eb.y, F1r * fb.y) : 0.f;
    float p6 = (mb &  64u) ? fmaxf(E1r * eb.z, F1r * fb.z) : 0.f;
    float p7 = (mb & 128u) ? fmaxf(E1r * eb.w, F1r * fb.w) : 0.f;
    return u4bf8(uint4{pk2(p0, p1), pk2(p2, p3), pk2(p4, p5), pk2(p6, p7)});
}

// ---------------------------------------------------------------------------
// KB: adj -> 64-bit masks. (Proven R8 kernel, unchanged.)
// ---------------------------------------------------------------------------
__global__ __launch_bounds__(256) void kb(const int* __restrict__ adj,
                                          unsigned long long* __restrict__ bits) {
    const int wv   = blockIdx.x * 4 + (threadIdx.x >> 6);
    const int lane = threadIdx.x & 63;
    const int base = wv * 32;
    #pragma unroll
    for (int r = 0; r < 4; ++r) {
        int v0 = adj[(size_t)(base + r*8 + 0) * 64 + lane];
        int v1 = adj[(size_t)(base + r*8 + 1) * 64 + lane];
        int v2 = adj[(size_t)(base + r*8 + 2) * 64 + lane];
        int v3 = adj[(size_t)(base + r*8 + 3) * 64 + lane];
        int v4 = adj[(size_t)(base + r*8 + 4) * 64 + lane];
        int v5 = adj[(size_t)(base + r*8 + 5) * 64 + lane];
        int v6 = adj[(size_t)(base + r*8 + 6) * 64 + lane];
        int v7 = adj[(size_t)(base + r*8 + 7) * 64 + lane];
        unsigned long long m0 = __ballot(v0 > 0);
        unsigned long long m1 = __ballot(v1 > 0);
        unsigned long long m2 = __ballot(v2 > 0);
        unsigned long long m3 = __ballot(v3 > 0);
        unsigned long long m4 = __ballot(v4 > 0);
        unsigned long long m5 = __ballot(v5 > 0);
        unsigned long long m6 = __ballot(v6 > 0);
        unsigned long long m7 = __ballot(v7 > 0);
        if (lane == 0) {
            ulonglong2* dst = (ulonglong2*)&bits[base + r*8];
            dst[0] = {m0, m1};
            dst[1] = {m2, m3};
            dst[2] = {m4, m5};
            dst[3] = {m6, m7};
        }
    }
}

// ---------------------------------------------------------------------------
// KG: Wh GEMM + WhTs epilogue + exp2-factor arrays E1,F1,E2,F2. (R13 kernel.)
// ---------------------------------------------------------------------------
__global__ __launch_bounds__(256) void kg(const float* __restrict__ x,
                                          const float* __restrict__ W,
                                          const float* __restrict__ aw,
                                          unsigned short* __restrict__ WhTs,
                                          float* __restrict__ E1,
                                          float* __restrict__ F1,
                                          float* __restrict__ E2,
                                          float* __restrict__ F2) {
    __shared__ float As[16][68];
    __shared__ float Bs[16][68];
    __shared__ unsigned short Tb[64][80];
    __shared__ float r1[64][16];
    __shared__ float r2[64][16];
    const int t = threadIdx.x;
    const int bx   = blockIdx.x;             // 0..511
    const int h    = bx >> 6;
    const int nti  = bx & 63;
    const int row0 = nti * 64;
    const int tr = t >> 4, tc = t & 15;
    const int ar = t >> 2, ak = t & 3;
    const int bk = t >> 4, bo = t & 15;
    const float* WH = W + (size_t)h * FIN * FOUT;
    float acc[4][4] = {};

    for (int k0i = 0; k0i < FIN; k0i += 16) {
        __syncthreads();
        float4 av = *(const float4*)&x[(size_t)(row0 + ar) * FIN + k0i + ak * 4];
        As[ak*4+0][ar] = av.x; As[ak*4+1][ar] = av.y;
        As[ak*4+2][ar] = av.z; As[ak*4+3][ar] = av.w;
        *(float4*)&Bs[bk][bo*4] =
            *(const float4*)&WH[(size_t)(k0i + bk) * FOUT + bo*4];
        __syncthreads();
        #pragma unroll
        for (int kk = 0; kk < 16; ++kk) {
            float4 a4 = *(const float4*)&As[kk][tr*4];
            float4 b4 = *(const float4*)&Bs[kk][tc*4];
            float a[4] = {a4.x, a4.y, a4.z, a4.w};
            float b[4] = {b4.x, b4.y, b4.z, b4.w};
            #pragma unroll
            for (int i = 0; i < 4; ++i)
                #pragma unroll
                for (int j = 0; j < 4; ++j)
                    acc[i][j] = fmaf(a[i], b[j], acc[i][j]);
        }
    }

    float a1v[4], a2v[4];
    #pragma unroll
    for (int j = 0; j < 4; ++j) {
        a1v[j] = aw[h * 2 * FOUT + tc*4 + j];
        a2v[j] = aw[h * 2 * FOUT + FOUT + tc*4 + j];
    }
    #pragma unroll
    for (int i = 0; i < 4; ++i) {
        float s1 = 0.f, s2 = 0.f;
        #pragma unroll
        for (int j = 0; j < 4; ++j) {
            s1 = fmaf(acc[i][j], a1v[j], s1);
            s2 = fmaf(acc[i][j], a2v[j], s2);
            Tb[tc*4 + j][tr*4 + i] = f2bf(acc[i][j]);
        }
        r1[tr*4 + i][tc] = s1;
        r2[tr*4 + i][tc] = s2;
    }
    __syncthreads();
    if (t < 64) {
        float s1 = 0.f, s2 = 0.f;
        #pragma unroll
        for (int k = 0; k < 16; ++k) { s1 += r1[t][k]; s2 += r2[t][k]; }
        float a = s1 * LOG2E, b = s2 * LOG2E;
        E1[h * NN + row0 + t] = __builtin_amdgcn_exp2f(a);
        F1[h * NN + row0 + t] = __builtin_amdgcn_exp2f(ALPHA * a);
        E2[h * NN + row0 + t] = __builtin_amdgcn_exp2f(b);
        F2[h * NN + row0 + t] = __builtin_amdgcn_exp2f(ALPHA * b);
    }
    unsigned char* tileB = (unsigned char*)(WhTs + ((size_t)(h * 64) + nti) * 4096);
    #pragma unroll
    for (int i = 0; i < 2; ++i) {
        int c = t + i * 256;
        int o = c >> 3, nch = c & 7;
        *(uint4*)(tileB + o * 128 + ((nch * 16) ^ ((o & 7) << 4))) =
            *(const uint4*)&Tb[o][nch * 8];
    }
}

// ---------------------------------------------------------------------------
// K3: fused masked softmax + PV (bf16 MFMA), j-split. 2-barrier template,
// 512 thr / 8 waves / ROWS=128. P built directly in NAMED A-fragment regs
// (af0, af1 — R13's union array spilled to scratch, 226 MB of it).
// Denominator via MFMA with constant ones-B fragment.
// ---------------------------------------------------------------------------
__global__ __launch_bounds__(512, 8) void k3_attn(
        const unsigned long long* __restrict__ bits,
        const unsigned short* __restrict__ WhTs,
        const float* __restrict__ E1, const float* __restrict__ F1,
        const float* __restrict__ E2, const float* __restrict__ F2,
        float* __restrict__ pnum, float* __restrict__ pden) {
    __shared__ unsigned char wsB[8192];
    const int t    = threadIdx.x;
    const int lane = t & 63, wid = t >> 6;      // 8 waves
    const int h    = blockIdx.y;
    const int row0 = blockIdx.x * ROWS;
    const int js   = blockIdx.z, JS = gridDim.z;
    const int ntile = (NN / 64) / JS;
    const int nt0   = js * ntile;
    const int myrow = wid * 16 + (lane & 15);   // block-local row 0..127
    const int kq    = lane >> 4;                // col-quarter 0..3
    const float E1r = E1[h * NN + row0 + myrow];
    const float F1r = F1[h * NN + row0 + myrow];
    const float* E2h = E2 + h * NN;
    const float* F2h = F2 + h * NN;
    const unsigned long long* bitsRow = bits + (size_t)(row0 + myrow) * 64;
    const unsigned short* WTS = WhTs + (size_t)h * 64 * 4096;
    f32x4 acc[4] = {};
    f32x4 accd = {};
    const bf16x8 ones = {0x3F80, 0x3F80, 0x3F80, 0x3F80,
                         0x3F80, 0x3F80, 0x3F80, 0x3F80};   // bf16 1.0 x8

    uint4 wreg;
    auto loadW = [&](int nti, uint4& w0) {
        w0 = ((const uint4*)(WTS + (size_t)nti * 4096))[t];   // 512 x 16B = 8 KB
    };
    loadW(nt0, wreg);

    const int kbyte = kq * 16;
    for (int it = 0; it < ntile; ++it) {
        const int nti = nt0 + it;
        __syncthreads();                       // prev MFMA done reading wsB
        *(uint4*)&wsB[t * 16] = wreg;
        // ---- P directly into named A-fragment registers ----
        const unsigned long long m64 = bitsRow[nti];
        const int cbase = nti * 64 + kq * 8;
        bf16x8 af0 = mkaf(E1r, F1r, E2h + cbase,      F2h + cbase,
                          (unsigned)(m64 >> (kq * 8)) & 0xFFu);
        bf16x8 af1 = mkaf(E1r, F1r, E2h + cbase + 32, F2h + cbase + 32,
                          (unsigned)(m64 >> (32 + kq * 8)) & 0xFFu);
        if (it + 1 < ntile) loadW(nti + 1, wreg);
        __syncthreads();                       // wsB visible
        // ---- MFMA, manually unrolled over the two k-steps ----
        accd = __builtin_amdgcn_mfma_f32_16x16x32_bf16(af0, ones, accd, 0, 0, 0);
        #pragma unroll
        for (int cf = 0; cf < 4; ++cf) {
            int brw = cf * 16 + (lane & 15);
            bf16x8 b0 = *(const bf16x8*)&wsB[brw * 128 + ((kbyte) ^ ((brw & 7) << 4))];
            acc[cf] = __builtin_amdgcn_mfma_f32_16x16x32_bf16(af0, b0, acc[cf], 0, 0, 0);
        }
        accd = __builtin_amdgcn_mfma_f32_16x16x32_bf16(af1, ones, accd, 0, 0, 0);
        #pragma unroll
        for (int cf = 0; cf < 4; ++cf) {
            int brw = cf * 16 + (lane & 15);
            bf16x8 b1 = *(const bf16x8*)&wsB[brw * 128 + ((64 + kbyte) ^ ((brw & 7) << 4))];
            acc[cf] = __builtin_amdgcn_mfma_f32_16x16x32_bf16(af1, b1, acc[cf], 0, 0, 0);
        }
    }

    float* pn = pnum + (((size_t)js * NH + h) * NN + row0) * 64;
    #pragma unroll
    for (int cf = 0; cf < 4; ++cf) {
        int o = cf * 16 + (lane & 15);
        #pragma unroll
        for (int rg = 0; rg < 4; ++rg) {
            int rl = wid * 16 + (lane >> 4) * 4 + rg;
            pn[(size_t)rl * 64 + o] = acc[cf][rg];
        }
    }
    if ((lane & 15) == 0) {                    // col-0 lanes hold den[row]
        float* pd = pden + ((size_t)js * NH + h) * NN + row0;
        #pragma unroll
        for (int rg = 0; rg < 4; ++rg)
            pd[wid * 16 + (lane >> 4) * 4 + rg] = accd[rg];
    }
}

// ---------------------------------------------------------------------------
// K4: reduce over JS slices + normalize.
// ---------------------------------------------------------------------------
__global__ __launch_bounds__(256) void k4_red(const float* __restrict__ pnum,
                                              const float* __restrict__ pden,
                                              float* __restrict__ out, int JS) {
    const int idx = blockIdx.x * 256 + threadIdx.x;   // 0..524287
    const int h   = idx >> 16;
    const int rem = idx & 65535;
    const int n   = rem >> 4;
    const int o4  = (rem & 15) * 4;
    float4 s = {0.f, 0.f, 0.f, 0.f};
    float  d = 0.f;
    for (int js = 0; js < JS; ++js) {
        const float* p = pnum + (((size_t)js * NH + h) * NN + n) * 64 + o4;
        float4 v = *(const float4*)p;
        s.x += v.x; s.y += v.y; s.z += v.z; s.w += v.w;
        d += pden[((size_t)js * NH + h) * NN + n];
    }
    float inv = 1.0f / d;
    float4 r = {s.x * inv, s.y * inv, s.z * inv, s.w * inv};
    *(float4*)&out[(size_t)n * (NH * FOUT) + h * FOUT + o4] = r;
}

extern "C" void kernel_launch(void* const* d_in, const int* in_sizes, int n_in,
                              void* d_out, int out_size, void* d_ws, size_t ws_size,
                              hipStream_t stream) {
    const float* x   = (const float*)d_in[0];
    const int*   adj = (const int*)d_in[1];
    const float* W   = (const float*)d_in[2];
    const float* a   = (const float*)d_in[3];
    float* outp = (float*)d_out;

    // workspace layout
    unsigned short* WhTs = (unsigned short*)d_ws;                   // 4 MB (tiled)
    float* E1 = (float*)(WhTs + (size_t)NH * 64 * NN);              // 128 KB each
    float* F1 = E1 + NH * NN;
    float* E2 = F1 + NH * NN;
    float* F2 = E2 + NH * NN;
    unsigned long long* bits = (unsigned long long*)(F2 + NH * NN); // 2 MB
    float* pnum = (float*)(bits + (size_t)NN * 64);
    const size_t baseBytes  = (size_t)((char*)pnum - (char*)d_ws);
    const size_t sliceBytes = (size_t)NH * NN * 65 * 4;             // num+den per slice
    int JS = 1;
    if (ws_size >= baseBytes + 4 * sliceBytes) JS = 4;
    else if (ws_size >= baseBytes + 2 * sliceBytes) JS = 2;
    float* pden = pnum + (size_t)JS * NH * NN * 64;

    kb     <<<dim3(2048),            256, 0, stream>>>(adj, bits);
    kg     <<<dim3(512),             256, 0, stream>>>(x, W, a, WhTs, E1, F1, E2, F2);
    k3_attn<<<dim3(NN/ROWS, NH, JS), 512, 0, stream>>>(bits, WhTs, E1, F1, E2, F2, pnum, pden);
    k4_red <<<dim3(NN*NH*FOUT/4/256), 256, 0, stream>>>(pnum, pden, outp, JS);
}

// Round 15
// 127.605 us; speedup vs baseline: 1.4914x; 1.4071x over previous
//
#include <hip/hip_runtime.h>
#include <hip/hip_bf16.h>

#define NN   4096
#define FIN  512
#define FOUT 64
#define NH   8
#define ALPHA 0.2f
#define ROWS 128
#define LOG2E 1.4426950408889634f

typedef __attribute__((ext_vector_type(8))) short bf16x8;
typedef __attribute__((ext_vector_type(4))) float f32x4;

__device__ __forceinline__ unsigned short f2bf(float x) {
    unsigned u = __float_as_uint(x);
    return (unsigned short)((u + 0x7fffu + ((u >> 16) & 1u)) >> 16);  // RNE
}

__device__ __forceinline__ unsigned pk2(float a, float b) {
    union { __hip_bfloat162 h2; unsigned u; } cv;
    cv.h2 = __float22bfloat162_rn(float2{a, b});   // low 16 = a (RNE)
    return cv.u;
}

__device__ __forceinline__ bf16x8 u4bf8(uint4 u) {   // scalar union: SROA-safe
    union { uint4 a; bf16x8 b; } cv; cv.a = u; return cv.b;
}

// Build one A-fragment (8 bf16 P values) from factored exp2 terms.
// p[j] = adjbit ? max(E1r*E2[j], F1r*F2[j]) : 0   (exp2∘lrelu factorized)
__device__ __forceinline__ bf16x8 mkaf(float E1r, float F1r,
                                       const float* __restrict__ E2p,
                                       const float* __restrict__ F2p,
                                       unsigned mb) {
    float4 ea = *(const float4*)E2p;
    float4 eb = *(const float4*)(E2p + 4);
    float4 fa = *(const float4*)F2p;
    float4 fb = *(const float4*)(F2p + 4);
    float p0 = (mb &   1u) ? fmaxf(E1r * ea.x, F1r * fa.x) : 0.f;
    float p1 = (mb &   2u) ? fmaxf(E1r * ea.y, F1r * fa.y) : 0.f;
    float p2 = (mb &   4u) ? fmaxf(E1r * ea.z, F1r * fa.z) : 0.f;
    float p3 = (mb &   8u) ? fmaxf(E1r * ea.w, F1r * fa.w) : 0.f;
    float p4 = (mb &  16u) ? fmaxf(E1r * eb.x, F1r * fb.x) : 0.f;
    float p5 = (mb &  32u) ? fmaxf(E1r * eb.y, F1r * fb.y) : 0.f;
    float p6 = (mb &  64u) ? fmaxf(E1r * eb.z, F1r * fb.z) : 0.f;
    float p7 = (mb & 128u) ? fmaxf(E1r * eb.w, F1r * fb.w) : 0.f;
    return u4bf8(uint4{pk2(p0, p1), pk2(p2, p3), pk2(p4, p5), pk2(p6, p7)});
}

// ---------------------------------------------------------------------------
// KB: adj -> 64-bit masks. (Proven R8 kernel, unchanged.)
// ---------------------------------------------------------------------------
__global__ __launch_bounds__(256) void kb(const int* __restrict__ adj,
                                          unsigned long long* __restrict__ bits) {
    const int wv   = blockIdx.x * 4 + (threadIdx.x >> 6);
    const int lane = threadIdx.x & 63;
    const int base = wv * 32;
    #pragma unroll
    for (int r = 0; r < 4; ++r) {
        int v0 = adj[(size_t)(base + r*8 + 0) * 64 + lane];
        int v1 = adj[(size_t)(base + r*8 + 1) * 64 + lane];
        int v2 = adj[(size_t)(base + r*8 + 2) * 64 + lane];
        int v3 = adj[(size_t)(base + r*8 + 3) * 64 + lane];
        int v4 = adj[(size_t)(base + r*8 + 4) * 64 + lane];
        int v5 = adj[(size_t)(base + r*8 + 5) * 64 + lane];
        int v6 = adj[(size_t)(base + r*8 + 6) * 64 + lane];
        int v7 = adj[(size_t)(base + r*8 + 7) * 64 + lane];
        unsigned long long m0 = __ballot(v0 > 0);
        unsigned long long m1 = __ballot(v1 > 0);
        unsigned long long m2 = __ballot(v2 > 0);
        unsigned long long m3 = __ballot(v3 > 0);
        unsigned long long m4 = __ballot(v4 > 0);
        unsigned long long m5 = __ballot(v5 > 0);
        unsigned long long m6 = __ballot(v6 > 0);
        unsigned long long m7 = __ballot(v7 > 0);
        if (lane == 0) {
            ulonglong2* dst = (ulonglong2*)&bits[base + r*8];
            dst[0] = {m0, m1};
            dst[1] = {m2, m3};
            dst[2] = {m4, m5};
            dst[3] = {m6, m7};
        }
    }
}

// ---------------------------------------------------------------------------
// KG: Wh GEMM + WhTs epilogue + exp2-factor arrays E1,F1,E2,F2. (Unchanged.)
// ---------------------------------------------------------------------------
__global__ __launch_bounds__(256) void kg(const float* __restrict__ x,
                                          const float* __restrict__ W,
                                          const float* __restrict__ aw,
                                          unsigned short* __restrict__ WhTs,
                                          float* __restrict__ E1,
                                          float* __restrict__ F1,
                                          float* __restrict__ E2,
                                          float* __restrict__ F2) {
    __shared__ float As[16][68];
    __shared__ float Bs[16][68];
    __shared__ unsigned short Tb[64][80];
    __shared__ float r1[64][16];
    __shared__ float r2[64][16];
    const int t = threadIdx.x;
    const int bx   = blockIdx.x;             // 0..511
    const int h    = bx >> 6;
    const int nti  = bx & 63;
    const int row0 = nti * 64;
    const int tr = t >> 4, tc = t & 15;
    const int ar = t >> 2, ak = t & 3;
    const int bk = t >> 4, bo = t & 15;
    const float* WH = W + (size_t)h * FIN * FOUT;
    float acc[4][4] = {};

    for (int k0i = 0; k0i < FIN; k0i += 16) {
        __syncthreads();
        float4 av = *(const float4*)&x[(size_t)(row0 + ar) * FIN + k0i + ak * 4];
        As[ak*4+0][ar] = av.x; As[ak*4+1][ar] = av.y;
        As[ak*4+2][ar] = av.z; As[ak*4+3][ar] = av.w;
        *(float4*)&Bs[bk][bo*4] =
            *(const float4*)&WH[(size_t)(k0i + bk) * FOUT + bo*4];
        __syncthreads();
        #pragma unroll
        for (int kk = 0; kk < 16; ++kk) {
            float4 a4 = *(const float4*)&As[kk][tr*4];
            float4 b4 = *(const float4*)&Bs[kk][tc*4];
            float a[4] = {a4.x, a4.y, a4.z, a4.w};
            float b[4] = {b4.x, b4.y, b4.z, b4.w};
            #pragma unroll
            for (int i = 0; i < 4; ++i)
                #pragma unroll
                for (int j = 0; j < 4; ++j)
                    acc[i][j] = fmaf(a[i], b[j], acc[i][j]);
        }
    }

    float a1v[4], a2v[4];
    #pragma unroll
    for (int j = 0; j < 4; ++j) {
        a1v[j] = aw[h * 2 * FOUT + tc*4 + j];
        a2v[j] = aw[h * 2 * FOUT + FOUT + tc*4 + j];
    }
    #pragma unroll
    for (int i = 0; i < 4; ++i) {
        float s1 = 0.f, s2 = 0.f;
        #pragma unroll
        for (int j = 0; j < 4; ++j) {
            s1 = fmaf(acc[i][j], a1v[j], s1);
            s2 = fmaf(acc[i][j], a2v[j], s2);
            Tb[tc*4 + j][tr*4 + i] = f2bf(acc[i][j]);
        }
        r1[tr*4 + i][tc] = s1;
        r2[tr*4 + i][tc] = s2;
    }
    __syncthreads();
    if (t < 64) {
        float s1 = 0.f, s2 = 0.f;
        #pragma unroll
        for (int k = 0; k < 16; ++k) { s1 += r1[t][k]; s2 += r2[t][k]; }
        float a = s1 * LOG2E, b = s2 * LOG2E;
        E1[h * NN + row0 + t] = __builtin_amdgcn_exp2f(a);
        F1[h * NN + row0 + t] = __builtin_amdgcn_exp2f(ALPHA * a);
        E2[h * NN + row0 + t] = __builtin_amdgcn_exp2f(b);
        F2[h * NN + row0 + t] = __builtin_amdgcn_exp2f(ALPHA * b);
    }
    unsigned char* tileB = (unsigned char*)(WhTs + ((size_t)(h * 64) + nti) * 4096);
    #pragma unroll
    for (int i = 0; i < 2; ++i) {
        int c = t + i * 256;
        int o = c >> 3, nch = c & 7;
        *(uint4*)(tileB + o * 128 + ((nch * 16) ^ ((o & 7) << 4))) =
            *(const uint4*)&Tb[o][nch * 8];
    }
}

// ---------------------------------------------------------------------------
// K3: fused masked softmax + PV (bf16 MFMA), j-split. 2-barrier template,
// 512 thr / 8 waves / ROWS=128, named A-frags. __launch_bounds__(512, 6):
// R14's (512,8) imposed a 64-VGPR cap -> the allocator spilled one fragment
// per tile (141 MB scratch WRITE). (512,6) caps ~85 VGPR — fits the ~75
// live-peak, still 24 waves/CU.
// ---------------------------------------------------------------------------
__global__ __launch_bounds__(512, 6) void k3_attn(
        const unsigned long long* __restrict__ bits,
        const unsigned short* __restrict__ WhTs,
        const float* __restrict__ E1, const float* __restrict__ F1,
        const float* __restrict__ E2, const float* __restrict__ F2,
        float* __restrict__ pnum, float* __restrict__ pden) {
    __shared__ unsigned char wsB[8192];
    const int t    = threadIdx.x;
    const int lane = t & 63, wid = t >> 6;      // 8 waves
    const int h    = blockIdx.y;
    const int row0 = blockIdx.x * ROWS;
    const int js   = blockIdx.z, JS = gridDim.z;
    const int ntile = (NN / 64) / JS;
    const int nt0   = js * ntile;
    const int myrow = wid * 16 + (lane & 15);   // block-local row 0..127
    const int kq    = lane >> 4;                // col-quarter 0..3
    const float E1r = E1[h * NN + row0 + myrow];
    const float F1r = F1[h * NN + row0 + myrow];
    const float* E2h = E2 + h * NN;
    const float* F2h = F2 + h * NN;
    const unsigned long long* bitsRow = bits + (size_t)(row0 + myrow) * 64;
    const unsigned short* WTS = WhTs + (size_t)h * 64 * 4096;
    f32x4 acc[4] = {};
    f32x4 accd = {};
    const bf16x8 ones = {0x3F80, 0x3F80, 0x3F80, 0x3F80,
                         0x3F80, 0x3F80, 0x3F80, 0x3F80};   // bf16 1.0 x8

    uint4 wreg;
    auto loadW = [&](int nti, uint4& w0) {
        w0 = ((const uint4*)(WTS + (size_t)nti * 4096))[t];   // 512 x 16B = 8 KB
    };
    loadW(nt0, wreg);

    const int kbyte = kq * 16;
    for (int it = 0; it < ntile; ++it) {
        const int nti = nt0 + it;
        __syncthreads();                       // prev MFMA done reading wsB
        *(uint4*)&wsB[t * 16] = wreg;
        // ---- P directly into named A-fragment registers ----
        const unsigned long long m64 = bitsRow[nti];
        const int cbase = nti * 64 + kq * 8;
        bf16x8 af0 = mkaf(E1r, F1r, E2h + cbase,      F2h + cbase,
                          (unsigned)(m64 >> (kq * 8)) & 0xFFu);
        bf16x8 af1 = mkaf(E1r, F1r, E2h + cbase + 32, F2h + cbase + 32,
                          (unsigned)(m64 >> (32 + kq * 8)) & 0xFFu);
        if (it + 1 < ntile) loadW(nti + 1, wreg);
        __syncthreads();                       // wsB visible
        // ---- MFMA, manually unrolled over the two k-steps ----
        accd = __builtin_amdgcn_mfma_f32_16x16x32_bf16(af0, ones, accd, 0, 0, 0);
        #pragma unroll
        for (int cf = 0; cf < 4; ++cf) {
            int brw = cf * 16 + (lane & 15);
            bf16x8 b0 = *(const bf16x8*)&wsB[brw * 128 + ((kbyte) ^ ((brw & 7) << 4))];
            acc[cf] = __builtin_amdgcn_mfma_f32_16x16x32_bf16(af0, b0, acc[cf], 0, 0, 0);
        }
        accd = __builtin_amdgcn_mfma_f32_16x16x32_bf16(af1, ones, accd, 0, 0, 0);
        #pragma unroll
        for (int cf = 0; cf < 4; ++cf) {
            int brw = cf * 16 + (lane & 15);
            bf16x8 b1 = *(const bf16x8*)&wsB[brw * 128 + ((64 + kbyte) ^ ((brw & 7) << 4))];
            acc[cf] = __builtin_amdgcn_mfma_f32_16x16x32_bf16(af1, b1, acc[cf], 0, 0, 0);
        }
    }

    float* pn = pnum + (((size_t)js * NH + h) * NN + row0) * 64;
    #pragma unroll
    for (int cf = 0; cf < 4; ++cf) {
        int o = cf * 16 + (lane & 15);
        #pragma unroll
        for (int rg = 0; rg < 4; ++rg) {
            int rl = wid * 16 + (lane >> 4) * 4 + rg;
            pn[(size_t)rl * 64 + o] = acc[cf][rg];
        }
    }
    if ((lane & 15) == 0) {                    // col-0 lanes hold den[row]
        float* pd = pden + ((size_t)js * NH + h) * NN + row0;
        #pragma unroll
        for (int rg = 0; rg < 4; ++rg)
            pd[wid * 16 + (lane >> 4) * 4 + rg] = accd[rg];
    }
}

// ---------------------------------------------------------------------------
// K4: reduce over JS slices + normalize.
// ---------------------------------------------------------------------------
__global__ __launch_bounds__(256) void k4_red(const float* __restrict__ pnum,
                                              const float* __restrict__ pden,
                                              float* __restrict__ out, int JS) {
    const int idx = blockIdx.x * 256 + threadIdx.x;   // 0..524287
    const int h   = idx >> 16;
    const int rem = idx & 65535;
    const int n   = rem >> 4;
    const int o4  = (rem & 15) * 4;
    float4 s = {0.f, 0.f, 0.f, 0.f};
    float  d = 0.f;
    for (int js = 0; js < JS; ++js) {
        const float* p = pnum + (((size_t)js * NH + h) * NN + n) * 64 + o4;
        float4 v = *(const float4*)p;
        s.x += v.x; s.y += v.y; s.z += v.z; s.w += v.w;
        d += pden[((size_t)js * NH + h) * NN + n];
    }
    float inv = 1.0f / d;
    float4 r = {s.x * inv, s.y * inv, s.z * inv, s.w * inv};
    *(float4*)&out[(size_t)n * (NH * FOUT) + h * FOUT + o4] = r;
}

extern "C" void kernel_launch(void* const* d_in, const int* in_sizes, int n_in,
                              void* d_out, int out_size, void* d_ws, size_t ws_size,
                              hipStream_t stream) {
    const float* x   = (const float*)d_in[0];
    const int*   adj = (const int*)d_in[1];
    const float* W   = (const float*)d_in[2];
    const float* a   = (const float*)d_in[3];
    float* outp = (float*)d_out;

    // workspace layout
    unsigned short* WhTs = (unsigned short*)d_ws;                   // 4 MB (tiled)
    float* E1 = (float*)(WhTs + (size_t)NH * 64 * NN);              // 128 KB each
    float* F1 = E1 + NH * NN;
    float* E2 = F1 + NH * NN;
    float* F2 = E2 + NH * NN;
    unsigned long long* bits = (unsigned long long*)(F2 + NH * NN); // 2 MB
    float* pnum = (float*)(bits + (size_t)NN * 64);
    const size_t baseBytes  = (size_t)((char*)pnum - (char*)d_ws);
    const size_t sliceBytes = (size_t)NH * NN * 65 * 4;             // num+den per slice
    int JS = 1;
    if (ws_size >= baseBytes + 4 * sliceBytes) JS = 4;
    else if (ws_size >= baseBytes + 2 * sliceBytes) JS = 2;
    float* pden = pnum + (size_t)JS * NH * NN * 64;

    kb     <<<dim3(2048),            256, 0, stream>>>(adj, bits);
    kg     <<<dim3(512),             256, 0, stream>>>(x, W, a, WhTs, E1, F1, E2, F2);
    k3_attn<<<dim3(NN/ROWS, NH, JS), 512, 0, stream>>>(bits, WhTs, E1, F1, E2, F2, pnum, pden);
    k4_red <<<dim3(NN*NH*FOUT/4/256), 256, 0, stream>>>(pnum, pden, outp, JS);
}

// Round 16
// 116.215 us; speedup vs baseline: 1.6376x; 1.0980x over previous
//
#include <hip/hip_runtime.h>
#include <hip/hip_bf16.h>

#define NN   4096
#define FIN  512
#define FOUT 64
#define NH   8
#define ALPHA 0.2f
#define ROWS 128
#define LOG2E 1.4426950408889634f

typedef __attribute__((ext_vector_type(8))) short bf16x8;
typedef __attribute__((ext_vector_type(4))) float f32x4;

__device__ __forceinline__ unsigned short f2bf(float x) {
    unsigned u = __float_as_uint(x);
    return (unsigned short)((u + 0x7fffu + ((u >> 16) & 1u)) >> 16);  // RNE
}

__device__ __forceinline__ unsigned pk2(float a, float b) {
    union { __hip_bfloat162 h2; unsigned u; } cv;
    cv.h2 = __float22bfloat162_rn(float2{a, b});   // low 16 = a (RNE)
    return cv.u;
}

__device__ __forceinline__ bf16x8 u4bf8(uint4 u) {   // scalar union: SROA-safe
    union { uint4 a; bf16x8 b; } cv; cv.a = u; return cv.b;
}

// A-fragment from interleaved EF pairs: a_k = {E2[2k],F2[2k],E2[2k+1],F2[2k+1]}
// p[j] = adjbit ? max(E1r*E2[j], F1r*F2[j]) : 0   (exp2∘lrelu factorized)
__device__ __forceinline__ bf16x8 mkaf2(float E1r, float F1r,
                                        float4 a0, float4 a1,
                                        float4 a2, float4 a3, unsigned mb) {
    float p0 = (mb &   1u) ? fmaxf(E1r * a0.x, F1r * a0.y) : 0.f;
    float p1 = (mb &   2u) ? fmaxf(E1r * a0.z, F1r * a0.w) : 0.f;
    float p2 = (mb &   4u) ? fmaxf(E1r * a1.x, F1r * a1.y) : 0.f;
    float p3 = (mb &   8u) ? fmaxf(E1r * a1.z, F1r * a1.w) : 0.f;
    float p4 = (mb &  16u) ? fmaxf(E1r * a2.x, F1r * a2.y) : 0.f;
    float p5 = (mb &  32u) ? fmaxf(E1r * a2.z, F1r * a2.w) : 0.f;
    float p6 = (mb &  64u) ? fmaxf(E1r * a3.x, F1r * a3.y) : 0.f;
    float p7 = (mb & 128u) ? fmaxf(E1r * a3.z, F1r * a3.w) : 0.f;
    return u4bf8(uint4{pk2(p0, p1), pk2(p2, p3), pk2(p4, p5), pk2(p6, p7)});
}

// ---------------------------------------------------------------------------
// KB: adj -> 64-bit masks. (Proven R8 kernel, unchanged.)
// ---------------------------------------------------------------------------
__global__ __launch_bounds__(256) void kb(const int* __restrict__ adj,
                                          unsigned long long* __restrict__ bits) {
    const int wv   = blockIdx.x * 4 + (threadIdx.x >> 6);
    const int lane = threadIdx.x & 63;
    const int base = wv * 32;
    #pragma unroll
    for (int r = 0; r < 4; ++r) {
        int v0 = adj[(size_t)(base + r*8 + 0) * 64 + lane];
        int v1 = adj[(size_t)(base + r*8 + 1) * 64 + lane];
        int v2 = adj[(size_t)(base + r*8 + 2) * 64 + lane];
        int v3 = adj[(size_t)(base + r*8 + 3) * 64 + lane];
        int v4 = adj[(size_t)(base + r*8 + 4) * 64 + lane];
        int v5 = adj[(size_t)(base + r*8 + 5) * 64 + lane];
        int v6 = adj[(size_t)(base + r*8 + 6) * 64 + lane];
        int v7 = adj[(size_t)(base + r*8 + 7) * 64 + lane];
        unsigned long long m0 = __ballot(v0 > 0);
        unsigned long long m1 = __ballot(v1 > 0);
        unsigned long long m2 = __ballot(v2 > 0);
        unsigned long long m3 = __ballot(v3 > 0);
        unsigned long long m4 = __ballot(v4 > 0);
        unsigned long long m5 = __ballot(v5 > 0);
        unsigned long long m6 = __ballot(v6 > 0);
        unsigned long long m7 = __ballot(v7 > 0);
        if (lane == 0) {
            ulonglong2* dst = (ulonglong2*)&bits[base + r*8];
            dst[0] = {m0, m1};
            dst[1] = {m2, m3};
            dst[2] = {m4, m5};
            dst[3] = {m6, m7};
        }
    }
}

// ---------------------------------------------------------------------------
// KG: Wh GEMM + WhTs epilogue + E1,F1 arrays + interleaved EF2 pairs.
// ---------------------------------------------------------------------------
__global__ __launch_bounds__(256) void kg(const float* __restrict__ x,
                                          const float* __restrict__ W,
                                          const float* __restrict__ aw,
                                          unsigned short* __restrict__ WhTs,
                                          float* __restrict__ E1,
                                          float* __restrict__ F1,
                                          float* __restrict__ EF2) {
    __shared__ float As[16][68];
    __shared__ float Bs[16][68];
    __shared__ unsigned short Tb[64][80];
    __shared__ float r1[64][16];
    __shared__ float r2[64][16];
    const int t = threadIdx.x;
    const int bx   = blockIdx.x;             // 0..511
    const int h    = bx >> 6;
    const int nti  = bx & 63;
    const int row0 = nti * 64;
    const int tr = t >> 4, tc = t & 15;
    const int ar = t >> 2, ak = t & 3;
    const int bk = t >> 4, bo = t & 15;
    const float* WH = W + (size_t)h * FIN * FOUT;
    float acc[4][4] = {};

    for (int k0i = 0; k0i < FIN; k0i += 16) {
        __syncthreads();
        float4 av = *(const float4*)&x[(size_t)(row0 + ar) * FIN + k0i + ak * 4];
        As[ak*4+0][ar] = av.x; As[ak*4+1][ar] = av.y;
        As[ak*4+2][ar] = av.z; As[ak*4+3][ar] = av.w;
        *(float4*)&Bs[bk][bo*4] =
            *(const float4*)&WH[(size_t)(k0i + bk) * FOUT + bo*4];
        __syncthreads();
        #pragma unroll
        for (int kk = 0; kk < 16; ++kk) {
            float4 a4 = *(const float4*)&As[kk][tr*4];
            float4 b4 = *(const float4*)&Bs[kk][tc*4];
            float a[4] = {a4.x, a4.y, a4.z, a4.w};
            float b[4] = {b4.x, b4.y, b4.z, b4.w};
            #pragma unroll
            for (int i = 0; i < 4; ++i)
                #pragma unroll
                for (int j = 0; j < 4; ++j)
                    acc[i][j] = fmaf(a[i], b[j], acc[i][j]);
        }
    }

    float a1v[4], a2v[4];
    #pragma unroll
    for (int j = 0; j < 4; ++j) {
        a1v[j] = aw[h * 2 * FOUT + tc*4 + j];
        a2v[j] = aw[h * 2 * FOUT + FOUT + tc*4 + j];
    }
    #pragma unroll
    for (int i = 0; i < 4; ++i) {
        float s1 = 0.f, s2 = 0.f;
        #pragma unroll
        for (int j = 0; j < 4; ++j) {
            s1 = fmaf(acc[i][j], a1v[j], s1);
            s2 = fmaf(acc[i][j], a2v[j], s2);
            Tb[tc*4 + j][tr*4 + i] = f2bf(acc[i][j]);
        }
        r1[tr*4 + i][tc] = s1;
        r2[tr*4 + i][tc] = s2;
    }
    __syncthreads();
    if (t < 64) {
        float s1 = 0.f, s2 = 0.f;
        #pragma unroll
        for (int k = 0; k < 16; ++k) { s1 += r1[t][k]; s2 += r2[t][k]; }
        float a = s1 * LOG2E, b = s2 * LOG2E;
        E1[h * NN + row0 + t] = __builtin_amdgcn_exp2f(a);
        F1[h * NN + row0 + t] = __builtin_amdgcn_exp2f(ALPHA * a);
        float2 ef = {__builtin_amdgcn_exp2f(b), __builtin_amdgcn_exp2f(ALPHA * b)};
        *(float2*)&EF2[(size_t)h * NN * 2 + (size_t)(row0 + t) * 2] = ef;
    }
    unsigned char* tileB = (unsigned char*)(WhTs + ((size_t)(h * 64) + nti) * 4096);
    #pragma unroll
    for (int i = 0; i < 2; ++i) {
        int c = t + i * 256;
        int o = c >> 3, nch = c & 7;
        *(uint4*)(tileB + o * 128 + ((nch * 16) ^ ((o & 7) << 4))) =
            *(const uint4*)&Tb[o][nch * 8];
    }
}

// ---------------------------------------------------------------------------
// K3: fused masked softmax + PV (bf16 MFMA), j-split. 2-barrier template,
// 512 thr / 8 waves / ROWS=128. All per-tile inputs (Wh chunk, EF pairs,
// bits mask) register-prefetched one tile ahead in NAMED regs — the P-phase
// between barriers is pure VALU (R15 exposed the EF loads' L2 latency there).
// Denominator via MFMA with constant ones-B fragment.
// ---------------------------------------------------------------------------
__global__ __launch_bounds__(512, 4) void k3_attn(
        const unsigned long long* __restrict__ bits,
        const unsigned short* __restrict__ WhTs,
        const float* __restrict__ E1, const float* __restrict__ F1,
        const float* __restrict__ EF2,
        float* __restrict__ pnum, float* __restrict__ pden) {
    __shared__ unsigned char wsB[8192];
    const int t    = threadIdx.x;
    const int lane = t & 63, wid = t >> 6;      // 8 waves
    const int h    = blockIdx.y;
    const int row0 = blockIdx.x * ROWS;
    const int js   = blockIdx.z, JS = gridDim.z;
    const int ntile = (NN / 64) / JS;
    const int nt0   = js * ntile;
    const int myrow = wid * 16 + (lane & 15);   // block-local row 0..127
    const int kq    = lane >> 4;                // col-quarter 0..3
    const float E1r = E1[h * NN + row0 + myrow];
    const float F1r = F1[h * NN + row0 + myrow];
    const unsigned long long* bitsRow = bits + (size_t)(row0 + myrow) * 64;
    const unsigned short* WTS = WhTs + (size_t)h * 64 * 4096;
    const float4* EFb = (const float4*)(EF2 + (size_t)h * NN * 2);
    f32x4 acc[4] = {};
    f32x4 accd = {};
    const bf16x8 ones = {0x3F80, 0x3F80, 0x3F80, 0x3F80,
                         0x3F80, 0x3F80, 0x3F80, 0x3F80};   // bf16 1.0 x8

    // prefetched state (named regs only — rule #20)
    uint4 wreg;
    float4 ca0, ca1, ca2, ca3, cb0, cb1, cb2, cb3;
    unsigned long long mcur;
    {
        wreg = ((const uint4*)(WTS + (size_t)nt0 * 4096))[t];
        const float4* p = EFb + nt0 * 32 + kq * 4;   // 8 j's (ks=0)
        ca0 = p[0];  ca1 = p[1];  ca2 = p[2];  ca3 = p[3];
        cb0 = p[16]; cb1 = p[17]; cb2 = p[18]; cb3 = p[19];  // ks=1 (+32 j's)
        mcur = bitsRow[nt0];
    }

    const int kbyte = kq * 16;
    for (int it = 0; it < ntile; ++it) {
        const int nti = nt0 + it;
        __syncthreads();                       // prev MFMA done reading wsB
        *(uint4*)&wsB[t * 16] = wreg;
        // ---- P from prefetched regs (pure VALU) ----
        bf16x8 af0 = mkaf2(E1r, F1r, ca0, ca1, ca2, ca3,
                           (unsigned)(mcur >> (kq * 8)) & 0xFFu);
        bf16x8 af1 = mkaf2(E1r, F1r, cb0, cb1, cb2, cb3,
                           (unsigned)(mcur >> (32 + kq * 8)) & 0xFFu);
        // ---- issue next tile's prefetch (covered by MFMA + barriers) ----
        if (it + 1 < ntile) {
            wreg = ((const uint4*)(WTS + (size_t)(nti + 1) * 4096))[t];
            const float4* p = EFb + (nti + 1) * 32 + kq * 4;
            ca0 = p[0];  ca1 = p[1];  ca2 = p[2];  ca3 = p[3];
            cb0 = p[16]; cb1 = p[17]; cb2 = p[18]; cb3 = p[19];
            mcur = bitsRow[nti + 1];
        }
        __syncthreads();                       // wsB visible
        // ---- MFMA, manually unrolled over the two k-steps ----
        accd = __builtin_amdgcn_mfma_f32_16x16x32_bf16(af0, ones, accd, 0, 0, 0);
        #pragma unroll
        for (int cf = 0; cf < 4; ++cf) {
            int brw = cf * 16 + (lane & 15);
            bf16x8 b0 = *(const bf16x8*)&wsB[brw * 128 + ((kbyte) ^ ((brw & 7) << 4))];
            acc[cf] = __builtin_amdgcn_mfma_f32_16x16x32_bf16(af0, b0, acc[cf], 0, 0, 0);
        }
        accd = __builtin_amdgcn_mfma_f32_16x16x32_bf16(af1, ones, accd, 0, 0, 0);
        #pragma unroll
        for (int cf = 0; cf < 4; ++cf) {
            int brw = cf * 16 + (lane & 15);
            bf16x8 b1 = *(const bf16x8*)&wsB[brw * 128 + ((64 + kbyte) ^ ((brw & 7) << 4))];
            acc[cf] = __builtin_amdgcn_mfma_f32_16x16x32_bf16(af1, b1, acc[cf], 0, 0, 0);
        }
    }

    float* pn = pnum + (((size_t)js * NH + h) * NN + row0) * 64;
    #pragma unroll
    for (int cf = 0; cf < 4; ++cf) {
        int o = cf * 16 + (lane & 15);
        #pragma unroll
        for (int rg = 0; rg < 4; ++rg) {
            int rl = wid * 16 + (lane >> 4) * 4 + rg;
            pn[(size_t)rl * 64 + o] = acc[cf][rg];
        }
    }
    if ((lane & 15) == 0) {                    // col-0 lanes hold den[row]
        float* pd = pden + ((size_t)js * NH + h) * NN + row0;
        #pragma unroll
        for (int rg = 0; rg < 4; ++rg)
            pd[wid * 16 + (lane >> 4) * 4 + rg] = accd[rg];
    }
}

// ---------------------------------------------------------------------------
// K4: reduce over JS slices + normalize.
// ---------------------------------------------------------------------------
__global__ __launch_bounds__(256) void k4_red(const float* __restrict__ pnum,
                                              const float* __restrict__ pden,
                                              float* __restrict__ out, int JS) {
    const int idx = blockIdx.x * 256 + threadIdx.x;   // 0..524287
    const int h   = idx >> 16;
    const int rem = idx & 65535;
    const int n   = rem >> 4;
    const int o4  = (rem & 15) * 4;
    float4 s = {0.f, 0.f, 0.f, 0.f};
    float  d = 0.f;
    for (int js = 0; js < JS; ++js) {
        const float* p = pnum + (((size_t)js * NH + h) * NN + n) * 64 + o4;
        float4 v = *(const float4*)p;
        s.x += v.x; s.y += v.y; s.z += v.z; s.w += v.w;
        d += pden[((size_t)js * NH + h) * NN + n];
    }
    float inv = 1.0f / d;
    float4 r = {s.x * inv, s.y * inv, s.z * inv, s.w * inv};
    *(float4*)&out[(size_t)n * (NH * FOUT) + h * FOUT + o4] = r;
}

extern "C" void kernel_launch(void* const* d_in, const int* in_sizes, int n_in,
                              void* d_out, int out_size, void* d_ws, size_t ws_size,
                              hipStream_t stream) {
    const float* x   = (const float*)d_in[0];
    const int*   adj = (const int*)d_in[1];
    const float* W   = (const float*)d_in[2];
    const float* a   = (const float*)d_in[3];
    float* outp = (float*)d_out;

    // workspace layout
    unsigned short* WhTs = (unsigned short*)d_ws;                   // 4 MB (tiled)
    float* E1  = (float*)(WhTs + (size_t)NH * 64 * NN);             // 128 KB
    float* F1  = E1 + NH * NN;                                      // 128 KB
    float* EF2 = F1 + NH * NN;                                      // 256 KB
    unsigned long long* bits = (unsigned long long*)(EF2 + (size_t)NH * NN * 2); // 2 MB
    float* pnum = (float*)(bits + (size_t)NN * 64);
    const size_t baseBytes  = (size_t)((char*)pnum - (char*)d_ws);
    const size_t sliceBytes = (size_t)NH * NN * 65 * 4;             // num+den per slice
    int JS = 1;
    if (ws_size >= baseBytes + 4 * sliceBytes) JS = 4;
    else if (ws_size >= baseBytes + 2 * sliceBytes) JS = 2;
    float* pden = pnum + (size_t)JS * NH * NN * 64;

    kb     <<<dim3(2048),            256, 0, stream>>>(adj, bits);
    kg     <<<dim3(512),             256, 0, stream>>>(x, W, a, WhTs, E1, F1, EF2);
    k3_attn<<<dim3(NN/ROWS, NH, JS), 512, 0, stream>>>(bits, WhTs, E1, F1, EF2, pnum, pden);
    k4_red <<<dim3(NN*NH*FOUT/4/256), 256, 0, stream>>>(pnum, pden, outp, JS);
}

// Round 17
// 100.284 us; speedup vs baseline: 1.8977x; 1.1589x over previous
//
#include <hip/hip_runtime.h>
#include <hip/hip_bf16.h>

#define NN   4096
#define FIN  512
#define FOUT 64
#define NH   8
#define ALPHA 0.2f
#define ROWS 128
#define LOG2E 1.4426950408889634f

typedef __attribute__((ext_vector_type(8))) short bf16x8;
typedef __attribute__((ext_vector_type(4))) float f32x4;

__device__ __forceinline__ unsigned short f2bf(float x) {
    unsigned u = __float_as_uint(x);
    return (unsigned short)((u + 0x7fffu + ((u >> 16) & 1u)) >> 16);  // RNE
}

__device__ __forceinline__ unsigned pk2(float a, float b) {
    union { __hip_bfloat162 h2; unsigned u; } cv;
    cv.h2 = __float22bfloat162_rn(float2{a, b});   // low 16 = a (RNE)
    return cv.u;
}

__device__ __forceinline__ bf16x8 u4bf8(uint4 u) {   // scalar union: SROA-safe
    union { uint4 a; bf16x8 b; } cv; cv.a = u; return cv.b;
}

// ---------------------------------------------------------------------------
// KB: adj -> 64-bit masks. (Proven R8 kernel, unchanged.)
// ---------------------------------------------------------------------------
__global__ __launch_bounds__(256) void kb(const int* __restrict__ adj,
                                          unsigned long long* __restrict__ bits) {
    const int wv   = blockIdx.x * 4 + (threadIdx.x >> 6);
    const int lane = threadIdx.x & 63;
    const int base = wv * 32;
    #pragma unroll
    for (int r = 0; r < 4; ++r) {
        int v0 = adj[(size_t)(base + r*8 + 0) * 64 + lane];
        int v1 = adj[(size_t)(base + r*8 + 1) * 64 + lane];
        int v2 = adj[(size_t)(base + r*8 + 2) * 64 + lane];
        int v3 = adj[(size_t)(base + r*8 + 3) * 64 + lane];
        int v4 = adj[(size_t)(base + r*8 + 4) * 64 + lane];
        int v5 = adj[(size_t)(base + r*8 + 5) * 64 + lane];
        int v6 = adj[(size_t)(base + r*8 + 6) * 64 + lane];
        int v7 = adj[(size_t)(base + r*8 + 7) * 64 + lane];
        unsigned long long m0 = __ballot(v0 > 0);
        unsigned long long m1 = __ballot(v1 > 0);
        unsigned long long m2 = __ballot(v2 > 0);
        unsigned long long m3 = __ballot(v3 > 0);
        unsigned long long m4 = __ballot(v4 > 0);
        unsigned long long m5 = __ballot(v5 > 0);
        unsigned long long m6 = __ballot(v6 > 0);
        unsigned long long m7 = __ballot(v7 > 0);
        if (lane == 0) {
            ulonglong2* dst = (ulonglong2*)&bits[base + r*8];
            dst[0] = {m0, m1};
            dst[1] = {m2, m3};
            dst[2] = {m4, m5};
            dst[3] = {m6, m7};
        }
    }
}

// ---------------------------------------------------------------------------
// KW: W[h][k][o] fp32 -> WT[h][o][k] bf16 (B-operand for kg's MFMA).
// grid (8 ktiles, 8 heads) via blockIdx.x = h*8 + kt.
// ---------------------------------------------------------------------------
__global__ __launch_bounds__(256) void kw(const float* __restrict__ W,
                                          unsigned short* __restrict__ WT) {
    __shared__ unsigned short T[64][72];
    const int t  = threadIdx.x;
    const int h  = blockIdx.x >> 3;
    const int k0 = (blockIdx.x & 7) * 64;
    #pragma unroll
    for (int i = 0; i < 4; ++i) {
        int idx = t + i * 256;               // 0..1023: kk 0..63 x o4 0..15
        int kk = idx >> 4, o4 = (idx & 15) * 4;
        float4 v = *(const float4*)&W[((size_t)h * FIN + k0 + kk) * FOUT + o4];
        T[o4+0][kk] = f2bf(v.x); T[o4+1][kk] = f2bf(v.y);
        T[o4+2][kk] = f2bf(v.z); T[o4+3][kk] = f2bf(v.w);
    }
    __syncthreads();
    #pragma unroll
    for (int i = 0; i < 2; ++i) {
        int c = t + i * 256;                 // 0..511: o = c>>3, kch = (c&7)*8
        int o = c >> 3, kch = (c & 7) * 8;
        *(uint4*)&WT[((size_t)h * 64 + o) * FIN + k0 + kch] =
            *(const uint4*)&T[o][kch];
    }
}

// ---------------------------------------------------------------------------
// KG: Wh = x @ W via bf16 MFMA, ZERO staging LDS / zero K-loop barriers.
// Block = 64 rows x 1 head, 4 waves; wave owns 16 rows x 64 outs.
// A-frag: x row chunk fp32 -> bf16 on the fly; B-frag: direct 16B load from
// L2-resident WT[h][o][k]. acc C-layout (m89): col=lane&15, row=(l>>4)*4+rg.
// Epilogue (proven kg code): Tb transpose -> swizzled WhTs; r1/r2 -> f1/f2.
// ---------------------------------------------------------------------------
__global__ __launch_bounds__(256) void kg(const float* __restrict__ x,
                                          const unsigned short* __restrict__ WT,
                                          const float* __restrict__ aw,
                                          unsigned short* __restrict__ WhTs,
                                          float* __restrict__ f1,
                                          float* __restrict__ f2) {
    __shared__ unsigned short Tb[64][80];
    __shared__ float r1[64][16];
    __shared__ float r2[64][16];
    const int t = threadIdx.x, lane = t & 63, wid = t >> 6;
    const int h    = blockIdx.x >> 6;
    const int nti  = blockIdx.x & 63;
    const int row0 = nti * 64;
    const int lrow = wid * 16 + (lane & 15);       // A-frag row (block-local)
    const int kc   = (lane >> 4) * 8;              // k-chunk within 32-step
    const float* xr = x + (size_t)(row0 + lrow) * FIN;
    const unsigned short* WTh = WT + (size_t)h * 64 * FIN;
    f32x4 acc[4] = {};

    #pragma unroll 4
    for (int k0 = 0; k0 < FIN; k0 += 32) {
        float4 xa = *(const float4*)&xr[k0 + kc];
        float4 xb = *(const float4*)&xr[k0 + kc + 4];
        bf16x8 af = u4bf8(uint4{pk2(xa.x, xa.y), pk2(xa.z, xa.w),
                                pk2(xb.x, xb.y), pk2(xb.z, xb.w)});
        #pragma unroll
        for (int cf = 0; cf < 4; ++cf) {
            int o = cf * 16 + (lane & 15);
            bf16x8 bfr = *(const bf16x8*)&WTh[(size_t)o * FIN + k0 + kc];
            acc[cf] = __builtin_amdgcn_mfma_f32_16x16x32_bf16(af, bfr, acc[cf], 0, 0, 0);
        }
    }

    // epilogue: f1/f2 partials + bf16 transpose tile (from C-layout accs)
    float a1v[4], a2v[4];
    #pragma unroll
    for (int cf = 0; cf < 4; ++cf) {
        a1v[cf] = aw[h * 2 * FOUT + cf * 16 + (lane & 15)];
        a2v[cf] = aw[h * 2 * FOUT + FOUT + cf * 16 + (lane & 15)];
    }
    #pragma unroll
    for (int rg = 0; rg < 4; ++rg) {
        const int lr = wid * 16 + (lane >> 4) * 4 + rg;   // C row (block-local)
        float s1 = 0.f, s2 = 0.f;
        #pragma unroll
        for (int cf = 0; cf < 4; ++cf) {
            s1 = fmaf(acc[cf][rg], a1v[cf], s1);
            s2 = fmaf(acc[cf][rg], a2v[cf], s2);
            Tb[cf * 16 + (lane & 15)][lr] = f2bf(acc[cf][rg]);
        }
        r1[lr][lane & 15] = s1;
        r2[lr][lane & 15] = s2;
    }
    __syncthreads();
    if (t < 64) {
        float s1 = 0.f, s2 = 0.f;
        #pragma unroll
        for (int k = 0; k < 16; ++k) { s1 += r1[t][k]; s2 += r2[t][k]; }
        f1[h * NN + row0 + t] = s1 * LOG2E;   // prescale: exp(x)=exp2(x*log2e)
        f2[h * NN + row0 + t] = s2 * LOG2E;
    }
    // write tile in k3's swizzled byte order (pre-swizzled global source)
    unsigned char* tileB = (unsigned char*)(WhTs + ((size_t)(h * 64) + nti) * 4096);
    #pragma unroll
    for (int i = 0; i < 2; ++i) {
        int c = t + i * 256;
        int o = c >> 3, nch = c & 7;
        *(uint4*)(tileB + o * 128 + ((nch * 16) ^ ((o & 7) << 4))) =
            *(const uint4*)&Tb[o][nch * 8];
    }
}

// ---------------------------------------------------------------------------
// K3: fused masked softmax + PV (bf16 MFMA), j-split. R10-EXACT revert
// (measured 60.5 us): 2-barrier template, 256 thr / ROWS=128, exp2 P into
// swizzled psB, Wh register-prefetch, denominator via ones-B MFMA.
// ---------------------------------------------------------------------------
__global__ __launch_bounds__(256, 4) void k3_attn(
        const unsigned long long* __restrict__ bits,
        const unsigned short* __restrict__ WhTs,
        const float* __restrict__ f1, const float* __restrict__ f2,
        float* __restrict__ pnum, float* __restrict__ pden) {
    __shared__ unsigned char psB[ROWS * 128];   // 16 KB
    __shared__ unsigned char wsB[8192];         //  8 KB
    const int t    = threadIdx.x;
    const int lane = t & 63, wid = t >> 6;
    const int h    = blockIdx.y;
    const int row0 = blockIdx.x * ROWS;
    const int js   = blockIdx.z, JS = gridDim.z;
    const int ntile = (NN / 64) / JS;
    const int nt0   = js * ntile;
    const int pr   = t >> 1, psub = t & 1;     // row 0..127, j-half 0..1
    const float f1r = f1[h * NN + row0 + pr];
    const float* f2h = f2 + h * NN;
    const unsigned long long* bitsRow = bits + (size_t)(row0 + pr) * 64;
    const unsigned short* WTS = WhTs + (size_t)h * 64 * 4096;
    const int prswz = (pr & 7) << 4;
    f32x4 acc[2][4] = {};
    f32x4 accd[2] = {};
    const bf16x8 ones = {0x3F80, 0x3F80, 0x3F80, 0x3F80,
                         0x3F80, 0x3F80, 0x3F80, 0x3F80};   // bf16 1.0 x8

    uint4 wreg0, wreg1;
    auto loadW = [&](int nti, uint4& w0, uint4& w1) {
        const uint4* gt = (const uint4*)(WTS + (size_t)nti * 4096);
        w0 = gt[t];
        w1 = gt[t + 256];
    };
    loadW(nt0, wreg0, wreg1);

    const int kb2 = (lane >> 4) * 16;
    for (int it = 0; it < ntile; ++it) {
        const int nti = nt0 + it;
        __syncthreads();                       // prev MFMA done reading tiles
        *(uint4*)&wsB[t * 16]        = wreg0;
        *(uint4*)&wsB[t * 16 + 4096] = wreg1;
        {
            unsigned msk = (unsigned)(bitsRow[nti] >> (psub << 5));
            const float* f2c = f2h + nti * 64 + psub * 32;
            #pragma unroll
            for (int q = 0; q < 4; ++q) {
                unsigned pk[4];
                #pragma unroll
                for (int c2 = 0; c2 < 2; ++c2) {
                    float4 f4 = *(const float4*)&f2c[q * 8 + c2 * 4];
                    float e0 = f1r + f4.x, e1 = f1r + f4.y;
                    float e2 = f1r + f4.z, e3 = f1r + f4.w;
                    e0 = fmaxf(e0, ALPHA * e0); e1 = fmaxf(e1, ALPHA * e1);
                    e2 = fmaxf(e2, ALPHA * e2); e3 = fmaxf(e3, ALPHA * e3);
                    const int b = q * 8 + c2 * 4;
                    float p0 = ((msk >> (b+0)) & 1u) ? __builtin_amdgcn_exp2f(e0) : 0.f;
                    float p1 = ((msk >> (b+1)) & 1u) ? __builtin_amdgcn_exp2f(e1) : 0.f;
                    float p2 = ((msk >> (b+2)) & 1u) ? __builtin_amdgcn_exp2f(e2) : 0.f;
                    float p3 = ((msk >> (b+3)) & 1u) ? __builtin_amdgcn_exp2f(e3) : 0.f;
                    pk[c2*2+0] = pk2(p0, p1);
                    pk[c2*2+1] = pk2(p2, p3);
                }
                uint4 w = {pk[0], pk[1], pk[2], pk[3]};
                *(uint4*)&psB[pr * 128 + ((psub*64 + q*16) ^ prswz)] = w;
            }
        }
        if (it + 1 < ntile) loadW(nti + 1, wreg0, wreg1);
        __syncthreads();                       // tiles visible
        #pragma unroll
        for (int fg = 0; fg < 2; ++fg) {
            const int arw  = wid * 32 + fg * 16 + (lane & 15);
            const int aswz = (arw & 7) << 4;
            #pragma unroll
            for (int ks = 0; ks < 2; ++ks) {
                bf16x8 af = *(const bf16x8*)&psB[arw * 128 + ((ks*64 + kb2) ^ aswz)];
                accd[fg] = __builtin_amdgcn_mfma_f32_16x16x32_bf16(af, ones, accd[fg], 0, 0, 0);
                #pragma unroll
                for (int cf = 0; cf < 4; ++cf) {
                    int brw = cf * 16 + (lane & 15);
                    bf16x8 bfr = *(const bf16x8*)&wsB[brw * 128 + ((ks*64 + kb2) ^ ((brw & 7) << 4))];
                    acc[fg][cf] = __builtin_amdgcn_mfma_f32_16x16x32_bf16(af, bfr, acc[fg][cf], 0, 0, 0);
                }
            }
        }
    }

    float* pn = pnum + (((size_t)js * NH + h) * NN + row0) * 64;
    #pragma unroll
    for (int fg = 0; fg < 2; ++fg)
        #pragma unroll
        for (int cf = 0; cf < 4; ++cf) {
            int o = cf * 16 + (lane & 15);
            #pragma unroll
            for (int rg = 0; rg < 4; ++rg) {
                int rl = wid * 32 + fg * 16 + (lane >> 4) * 4 + rg;
                pn[(size_t)rl * 64 + o] = acc[fg][cf][rg];
            }
        }
    if ((lane & 15) == 0) {                    // col-0 lanes hold den[row]
        float* pd = pden + ((size_t)js * NH + h) * NN + row0;
        #pragma unroll
        for (int fg = 0; fg < 2; ++fg)
            #pragma unroll
            for (int rg = 0; rg < 4; ++rg)
                pd[wid * 32 + fg * 16 + (lane >> 4) * 4 + rg] = accd[fg][rg];
    }
}

// ---------------------------------------------------------------------------
// K4: reduce over JS slices + normalize.
// ---------------------------------------------------------------------------
__global__ __launch_bounds__(256) void k4_red(const float* __restrict__ pnum,
                                              const float* __restrict__ pden,
                                              float* __restrict__ out, int JS) {
    const int idx = blockIdx.x * 256 + threadIdx.x;   // 0..524287
    const int h   = idx >> 16;
    const int rem = idx & 65535;
    const int n   = rem >> 4;
    const int o4  = (rem & 15) * 4;
    float4 s = {0.f, 0.f, 0.f, 0.f};
    float  d = 0.f;
    for (int js = 0; js < JS; ++js) {
        const float* p = pnum + (((size_t)js * NH + h) * NN + n) * 64 + o4;
        float4 v = *(const float4*)p;
        s.x += v.x; s.y += v.y; s.z += v.z; s.w += v.w;
        d += pden[((size_t)js * NH + h) * NN + n];
    }
    float inv = 1.0f / d;
    float4 r = {s.x * inv, s.y * inv, s.z * inv, s.w * inv};
    *(float4*)&out[(size_t)n * (NH * FOUT) + h * FOUT + o4] = r;
}

extern "C" void kernel_launch(void* const* d_in, const int* in_sizes, int n_in,
                              void* d_out, int out_size, void* d_ws, size_t ws_size,
                              hipStream_t stream) {
    const float* x   = (const float*)d_in[0];
    const int*   adj = (const int*)d_in[1];
    const float* W   = (const float*)d_in[2];
    const float* a   = (const float*)d_in[3];
    float* outp = (float*)d_out;

    // workspace layout
    unsigned short* WhTs = (unsigned short*)d_ws;                   // 4 MB (tiled)
    float* f1 = (float*)(WhTs + (size_t)NH * 64 * NN);              // 128 KB
    float* f2 = f1 + NH * NN;                                       // 128 KB
    unsigned short* WT = (unsigned short*)(f2 + NH * NN);           // 512 KB bf16
    unsigned long long* bits = (unsigned long long*)(WT + (size_t)NH * 64 * FIN); // 2 MB
    float* pnum = (float*)(bits + (size_t)NN * 64);
    const size_t baseBytes  = (size_t)((char*)pnum - (char*)d_ws);
    const size_t sliceBytes = (size_t)NH * NN * 65 * 4;             // num+den per slice
    int JS = 1;
    if (ws_size >= baseBytes + 4 * sliceBytes) JS = 4;
    else if (ws_size >= baseBytes + 2 * sliceBytes) JS = 2;
    float* pden = pnum + (size_t)JS * NH * NN * 64;

    kb     <<<dim3(2048),            256, 0, stream>>>(adj, bits);
    kw     <<<dim3(64),              256, 0, stream>>>(W, WT);
    kg     <<<dim3(512),             256, 0, stream>>>(x, WT, a, WhTs, f1, f2);
    k3_attn<<<dim3(NN/ROWS, NH, JS), 256, 0, stream>>>(bits, WhTs, f1, f2, pnum, pden);
    k4_red <<<dim3(NN*NH*FOUT/4/256), 256, 0, stream>>>(pnum, pden, outp, JS);
}